// Round 4
// baseline (335.920 us; speedup 1.0000x reference)
//
#include <hip/hip_runtime.h>
#include <stdint.h>

static constexpr int THREADS = 256;
static constexpr int KLOG  = 14;              // 16384 keys per bucket
static constexpr int KPB   = 1 << KLOG;       // 64 KB fp32 LDS in pass C
static constexpr int KMASK = KPB - 1;
static constexpr int MAXNB = 32;

// fallback (R3) constants
static constexpr int SCAN_THREADS = 1024;
static constexpr int CM  = 16384;
static constexpr int CN  = 16384;
static constexpr int CSZ = CM + CN;
static constexpr int MAX_REP = 32;

typedef int   vint4   __attribute__((ext_vector_type(4)));
typedef float vfloat4 __attribute__((ext_vector_type(4)));
typedef unsigned long long u64;

// ---------------------------------------------------------------------------
// init: zero fp64 accumulators, output scalar, bucket counters.
// ---------------------------------------------------------------------------
__global__ void kkt_init(double* __restrict__ acc, float* __restrict__ out,
                         unsigned* __restrict__ gcnt, int nb) {
  int t = threadIdx.x;
  if (t < 4) acc[t] = 0.0;
  if (t == 0) out[0] = 0.0f;
  if (t < nb) gcnt[t] = 0u;
}

// ---------------------------------------------------------------------------
// Pass B: bin. One read of each edge; emit (key, a*x[c]) to row bucket and
// (key, a*lam[r]) to col bucket. Block-level reservation: wave-split LDS
// rank counters + one global atomicAdd per bucket per block-iter.
// ---------------------------------------------------------------------------
__global__ __launch_bounds__(THREADS) void kkt_bin(
    const int* __restrict__ rows, const int* __restrict__ cols,
    const float* __restrict__ attr,
    const float* __restrict__ x, const float* __restrict__ lam,
    u64* __restrict__ buckets, unsigned* __restrict__ gcnt,
    int E, int RB, int NB, long cap) {
  __shared__ unsigned lcnt[4][MAXNB];
  __shared__ unsigned woff[4][MAXNB];
  __shared__ unsigned lbase[MAXNB];
  const int tid = threadIdx.x;
  const int wv  = tid >> 6;
  const long gsz = (long)gridDim.x * THREADS;
  const long gid = (long)blockIdx.x * THREADS + tid;
  const long ntot4 = ((long)E + 3) >> 2;
  const int iters = (int)((ntot4 + gsz - 1) / gsz);

  const vint4*   rows4 = (const vint4*)rows;
  const vint4*   cols4 = (const vint4*)cols;
  const vfloat4* attr4 = (const vfloat4*)attr;

  for (int it = 0; it < iters; ++it) {
    long q  = (long)it * gsz + gid;   // vec4 index
    long i4 = q << 2;                 // first edge
    int nv = 0;
    if (i4 < E) { long rem = (long)E - i4; nv = rem >= 4 ? 4 : (int)rem; }

    int   r_[4], c_[4];
    float a_[4];
    if (nv == 4) {
      vint4   rr = __builtin_nontemporal_load(rows4 + q);
      vint4   cc = __builtin_nontemporal_load(cols4 + q);
      vfloat4 aa = __builtin_nontemporal_load(attr4 + q);
      r_[0]=rr.x; r_[1]=rr.y; r_[2]=rr.z; r_[3]=rr.w;
      c_[0]=cc.x; c_[1]=cc.y; c_[2]=cc.z; c_[3]=cc.w;
      a_[0]=aa.x; a_[1]=aa.y; a_[2]=aa.z; a_[3]=aa.w;
    } else {
      for (int j = 0; j < 4; ++j) {
        if (j < nv) { r_[j]=rows[i4+j]; c_[j]=cols[i4+j]; a_[j]=attr[i4+j]; }
        else        { r_[j]=0; c_[j]=0; a_[j]=0.0f; }
      }
    }

    int      bk[8];
    unsigned ky[8];
    float    vl[8];
    bool     ok[8];
#pragma unroll
    for (int e = 0; e < 8; ++e) {
      int j = e & 3;
      ok[e] = j < nv;
      if (e < 4) {           // row-side entry
        bk[e] = r_[j] >> KLOG;
        ky[e] = (unsigned)r_[j];
        vl[e] = ok[e] ? a_[j] * x[c_[j]] : 0.0f;
      } else {               // col-side entry
        bk[e] = RB + (c_[j] >> KLOG);
        ky[e] = (unsigned)c_[j];
        vl[e] = ok[e] ? a_[j] * lam[r_[j]] : 0.0f;
      }
    }

    // zero wave-split counters
    for (int i = tid; i < 4 * MAXNB; i += THREADS) ((unsigned*)lcnt)[i] = 0u;
    __syncthreads();

    unsigned rank[8];
#pragma unroll
    for (int e = 0; e < 8; ++e)
      if (ok[e]) rank[e] = atomicAdd(&lcnt[wv][bk[e]], 1u);
    __syncthreads();

    if (tid < NB) {
      unsigned tot = 0;
      for (int w = 0; w < 4; ++w) { woff[w][tid] = tot; tot += lcnt[w][tid]; }
      lbase[tid] = tot ? atomicAdd(&gcnt[tid], tot) : 0u;
    }
    __syncthreads();

#pragma unroll
    for (int e = 0; e < 8; ++e) {
      if (ok[e]) {
        long pos = (long)lbase[bk[e]] + woff[wv][bk[e]] + rank[e];
        if (pos < cap)
          buckets[(long)bk[e] * cap + pos] =
              ((u64)ky[e] << 32) | (u64)__float_as_uint(vl[e]);
      }
    }
    __syncthreads();
  }
}

// ---------------------------------------------------------------------------
// Pass C: accumulate one bucket slice into a 64 KB LDS array (ds_add_f32),
// flush to a private partial replica. Zero global atomics.
// ---------------------------------------------------------------------------
__global__ __launch_bounds__(1024) void kkt_bucket(
    const u64* __restrict__ buckets, const unsigned* __restrict__ gcnt,
    float* __restrict__ partial, long cap, int REP2) {
  __shared__ float lds[KPB];
  const int b = blockIdx.x / REP2;
  const int s = blockIdx.x % REP2;
  vfloat4* l4 = (vfloat4*)lds;
  for (int i = threadIdx.x; i < KPB / 4; i += 1024) l4[i] = (vfloat4)(0.0f);
  __syncthreads();

  long cnt = (long)gcnt[b];
  if (cnt > cap) cnt = cap;
  long per = (cnt + REP2 - 1) / REP2;
  long s0 = (long)s * per; if (s0 > cnt) s0 = cnt;
  long s1 = s0 + per;      if (s1 > cnt) s1 = cnt;

  const u64* base = buckets + (long)b * cap;
  for (long i = s0 + threadIdx.x; i < s1; i += 1024) {
    u64 e = base[i];
    unsafeAtomicAdd(&lds[(unsigned)(e >> 32) & KMASK],
                    __uint_as_float((unsigned)e));
  }
  __syncthreads();

  vfloat4* dst = (vfloat4*)(partial + (size_t)blockIdx.x * KPB);
  for (int i = threadIdx.x; i < KPB / 4; i += 1024) dst[i] = l4[i];
}

// ---------------------------------------------------------------------------
// Pass D: reduce partials + loss. seg_mean_sq(v).sum() == sum(v*v)/per.
// ---------------------------------------------------------------------------
__global__ __launch_bounds__(THREADS) void kkt_reduce_loss(
    const float* __restrict__ partial,
    const float* __restrict__ bcat, const float* __restrict__ ccat,
    const float* __restrict__ lam, double* __restrict__ acc,
    int sum_m, int sum_n, int RB, int REP2) {
  int idx = blockIdx.x * blockDim.x + threadIdx.x;
  int stride = gridDim.x * blockDim.x;
  double pr = 0.0, du = 0.0, st = 0.0, cs = 0.0;
  for (int i = idx; i < sum_m; i += stride) {
    int b = i >> KLOG, j = i & KMASK;
    const float* p0 = partial + (size_t)(b * REP2) * KPB + j;
    float ax = 0.0f;
    for (int s = 0; s < REP2; ++s) ax += p0[(size_t)s * KPB];
    float d  = ax - bcat[i];
    float li = lam[i];
    float pp   = d > 0.0f ? d : 0.0f;
    float u    = li < 0.0f ? -li : 0.0f;
    float comp = li * d;
    pr += (double)pp * pp;
    du += (double)u * u;
    cs += (double)comp * comp;
  }
  for (int i = idx; i < sum_n; i += stride) {
    int b = RB + (i >> KLOG), j = i & KMASK;
    const float* p0 = partial + (size_t)(b * REP2) * KPB + j;
    float at = 0.0f;
    for (int s = 0; s < REP2; ++s) at += p0[(size_t)s * KPB];
    float sv = at + ccat[i];
    st += (double)sv * sv;
  }
  for (int off = 32; off > 0; off >>= 1) {
    pr += __shfl_down(pr, off);
    du += __shfl_down(du, off);
    st += __shfl_down(st, off);
    cs += __shfl_down(cs, off);
  }
  if ((threadIdx.x & 63) == 0) {
    unsafeAtomicAdd(&acc[0], pr);
    unsafeAtomicAdd(&acc[1], du);
    unsafeAtomicAdd(&acc[2], st);
    unsafeAtomicAdd(&acc[3], cs);
  }
}

// ---------------------------------------------------------------------------
// Fallback (R3, proven 252 µs): chunked LDS scan. Used only if ws too small.
// ---------------------------------------------------------------------------
__global__ __launch_bounds__(SCAN_THREADS) void kkt_scan(
    const int* __restrict__ rows, const int* __restrict__ cols,
    const float* __restrict__ attr,
    const float* __restrict__ x, const float* __restrict__ lam,
    float* __restrict__ partial, int E, int REP) {
  __shared__ float lds[CSZ];
  const int p = blockIdx.x / REP;
  const int r = blockIdx.x % REP;
  const int baseM = p * CM;
  const int baseN = p * CN;
  vfloat4* l4 = (vfloat4*)lds;
  for (int i = threadIdx.x; i < CSZ / 4; i += SCAN_THREADS) l4[i] = (vfloat4)(0.0f);
  __syncthreads();
  long per = (((long)E + REP - 1) / REP + 3) & ~3L;
  long e0 = per * r;  if (e0 > E) e0 = E;
  long e1 = e0 + per; if (e1 > E) e1 = E;
  int  n4 = (int)((e1 - e0) >> 2);
  const vint4*   rows4 = (const vint4*)(rows + e0);
  const vint4*   cols4 = (const vint4*)(cols + e0);
  const vfloat4* attr4 = (const vfloat4*)(attr + e0);
#define EDGE_ACC(RR, CC, AA)                                                 \
  do {                                                                       \
    unsigned mm = (unsigned)((RR) - baseM);                                  \
    if (mm < (unsigned)CM) unsafeAtomicAdd(&lds[mm], (AA) * x[(CC)]);        \
    unsigned nn = (unsigned)((CC) - baseN);                                  \
    if (nn < (unsigned)CN) unsafeAtomicAdd(&lds[CM + nn], (AA) * lam[(RR)]); \
  } while (0)
  for (int i = threadIdx.x; i < n4; i += SCAN_THREADS) {
    vint4 rr = rows4[i]; vint4 cc = cols4[i]; vfloat4 aa = attr4[i];
    EDGE_ACC(rr.x, cc.x, aa.x);
    EDGE_ACC(rr.y, cc.y, aa.y);
    EDGE_ACC(rr.z, cc.z, aa.z);
    EDGE_ACC(rr.w, cc.w, aa.w);
  }
  for (long i = e0 + ((long)n4 << 2) + threadIdx.x; i < e1; i += SCAN_THREADS) {
    int rr = rows[i], cc = cols[i];
    float aa = attr[i];
    EDGE_ACC(rr, cc, aa);
  }
#undef EDGE_ACC
  __syncthreads();
  vfloat4* d4 = (vfloat4*)(partial + (size_t)(p * REP + r) * CSZ);
  for (int i = threadIdx.x; i < CSZ / 4; i += SCAN_THREADS) d4[i] = l4[i];
}

__global__ __launch_bounds__(THREADS) void kkt_scan_loss(
    const float* __restrict__ partial,
    const float* __restrict__ bcat, const float* __restrict__ ccat,
    const float* __restrict__ lam, double* __restrict__ acc,
    int sum_m, int sum_n, int REP) {
  int idx = blockIdx.x * blockDim.x + threadIdx.x;
  int stride = gridDim.x * blockDim.x;
  double pr = 0.0, du = 0.0, st = 0.0, cs = 0.0;
  for (int i = idx; i < sum_m; i += stride) {
    int p = i / CM, j = i - p * CM;
    const float* base = partial + (size_t)(p * REP) * CSZ + j;
    float ax = 0.0f;
    for (int rr = 0; rr < REP; ++rr) ax += base[(size_t)rr * CSZ];
    float d  = ax - bcat[i];
    float li = lam[i];
    float pp   = d > 0.0f ? d : 0.0f;
    float u    = li < 0.0f ? -li : 0.0f;
    float comp = li * d;
    pr += (double)pp * pp;
    du += (double)u * u;
    cs += (double)comp * comp;
  }
  for (int i = idx; i < sum_n; i += stride) {
    int p = i / CN, j = i - p * CN;
    const float* base = partial + (size_t)(p * REP) * CSZ + CM + j;
    float at = 0.0f;
    for (int rr = 0; rr < REP; ++rr) at += base[(size_t)rr * CSZ];
    float s = at + ccat[i];
    st += (double)s * s;
  }
  for (int off = 32; off > 0; off >>= 1) {
    pr += __shfl_down(pr, off);
    du += __shfl_down(du, off);
    st += __shfl_down(st, off);
    cs += __shfl_down(cs, off);
  }
  if ((threadIdx.x & 63) == 0) {
    unsafeAtomicAdd(&acc[0], pr);
    unsafeAtomicAdd(&acc[1], du);
    unsafeAtomicAdd(&acc[2], st);
    unsafeAtomicAdd(&acc[3], cs);
  }
}

// ---------------------------------------------------------------------------
// finalize
// ---------------------------------------------------------------------------
__global__ void kkt_finalize(const double* __restrict__ acc,
                             const int* __restrict__ Bp,
                             const int* __restrict__ mp,
                             const int* __restrict__ np_,
                             float* __restrict__ out) {
  double m = (double)mp[0];
  double n = (double)np_[0];
  double B = (double)Bp[0];
  double total =
      (0.1 * (acc[0] + acc[1]) / m + 0.6 * acc[2] / n + 0.2 * acc[3] / m) / B;
  out[0] = (float)total;
}

extern "C" void kernel_launch(void* const* d_in, const int* in_sizes, int n_in,
                              void* d_out, int out_size, void* d_ws, size_t ws_size,
                              hipStream_t stream) {
  const float* x    = (const float*)d_in[0];
  const float* lam  = (const float*)d_in[1];
  const int*   rows = (const int*)d_in[2];
  const int*   cols = (const int*)d_in[3];
  const float* attr = (const float*)d_in[4];
  const float* bcat = (const float*)d_in[5];
  const float* ccat = (const float*)d_in[6];
  const int*   Bp   = (const int*)d_in[7];
  const int*   mp   = (const int*)d_in[8];
  const int*   np_  = (const int*)d_in[9];

  const int sum_n = in_sizes[0];
  const int sum_m = in_sizes[1];
  const int E     = in_sizes[2];

  char*     ws   = (char*)d_ws;
  double*   acc  = (double*)ws;              // 32 B
  unsigned* gcnt = (unsigned*)(ws + 64);     // NB uints
  float*    out  = (float*)d_out;

  const int RB = (sum_m + KPB - 1) >> KLOG;
  const int CB = (sum_n + KPB - 1) >> KLOG;
  const int NB = RB + CB;

  long exp_per = (long)E / (RB < CB ? RB : CB);
  long cap_min = exp_per + exp_per / 16 + 4096;   // ~6% + slack margin

  int  REP2 = 0;
  long cap = 0, part_bytes = 0;
  const long off_part = 4096;
  if (NB <= MAXNB) {
    for (int r2 = 32; r2 >= 4; r2 >>= 1) {
      long pb  = (long)NB * r2 * KPB * 4;
      long rem = (long)ws_size - off_part - pb;
      long c   = rem > 0 ? rem / ((long)NB * 8) : 0;
      c &= ~1L;
      if (c >= cap_min) { REP2 = r2; cap = c; part_bytes = pb; break; }
    }
  }
  long cap_max = exp_per + exp_per / 4;
  if (REP2 && cap > cap_max) cap = cap_max & ~1L;

  if (REP2) {
    float* partial = (float*)(ws + off_part);
    u64*   buckets = (u64*)(ws + off_part + part_bytes);

    kkt_init<<<1, 64, 0, stream>>>(acc, out, gcnt, NB);
    kkt_bin<<<1024, THREADS, 0, stream>>>(rows, cols, attr, x, lam,
                                          buckets, gcnt, E, RB, NB, cap);
    kkt_bucket<<<NB * REP2, 1024, 0, stream>>>(buckets, gcnt, partial, cap, REP2);
    int lw = sum_m > sum_n ? sum_m : sum_n;
    int lb = (lw + THREADS - 1) / THREADS;
    if (lb > 1024) lb = 1024;
    kkt_reduce_loss<<<lb, THREADS, 0, stream>>>(partial, bcat, ccat, lam, acc,
                                                sum_m, sum_n, RB, REP2);
  } else {
    // R3 fallback: chunked LDS scan
    float* buf = (float*)(ws + 64);
    const int NPm = (sum_m + CM - 1) / CM;
    const int NPn = (sum_n + CN - 1) / CN;
    const int NP  = NPm > NPn ? NPm : NPn;
    size_t avail = ws_size > 64 ? ws_size - 64 : 0;
    int REP = (int)(avail / ((size_t)NP * CSZ * sizeof(float)));
    if (REP > MAX_REP) REP = MAX_REP;
    if (REP < 1) REP = 1;  // ws guaranteed at least this big in practice
    kkt_init<<<1, 64, 0, stream>>>(acc, out, gcnt, 0);
    kkt_scan<<<NP * REP, SCAN_THREADS, 0, stream>>>(rows, cols, attr, x, lam,
                                                    buf, E, REP);
    int lw = sum_m > sum_n ? sum_m : sum_n;
    int lb = (lw + THREADS - 1) / THREADS;
    if (lb > 1024) lb = 1024;
    kkt_scan_loss<<<lb, THREADS, 0, stream>>>(buf, bcat, ccat, lam, acc,
                                              sum_m, sum_n, REP);
  }
  kkt_finalize<<<1, 1, 0, stream>>>(acc, Bp, mp, np_, out);
}